// Round 5
// baseline (273.644 us; speedup 1.0000x reference)
//
#include <hip/hip_runtime.h>
#include <hip/hip_fp16.h>
#include <math.h>

#define N_NODES 50000
#define N_EDGES 1600000
#define NB 2000      // dst buckets; NB*NPB == N_NODES
#define NPB 25       // dst nodes per bucket (dstLocal in 5 bits)
#define NCH 100      // edge chunks
#define EPC 16000    // edges per chunk
#define CAPC 32      // slots per (bucket,chunk) cell: Poisson(8) + ~8 sigma
#define CAP_LDS 1280 // max edges per bucket (mean 800, +17 sigma)
#define SPLIT 4      // k_place: blocks per chunk (bucket-range partition)
#define BPS (NB / SPLIT)

// ---- workspace layout (bytes) ----
// h16    : 0           12,800,000  __half, QUARTER-MAJOR: [4][N_NODES][32]
// s_src  : 12,800,000     200,000  float[N]
// s_dst  : 13,000,000     200,000  float[N]
// cnt    : 13,200,000     800,000  int[NCH*NB] (chunk-major, fully rewritten)
// gep    : 14,000,000  25,600,000  u32[NB*NCH*CAPC] ((src<<5)|dstLocal)
// total 39,600,000 B (proven size)

// h = (feat * sigmoid(mask)) @ W + b, fp32 math, fp16 store (quarter-major).
__global__ __launch_bounds__(256) void k_project(const float* __restrict__ feat,
                                                 const float* __restrict__ W,
                                                 const float* __restrict__ b,
                                                 const float* __restrict__ mask,
                                                 __half* __restrict__ h16) {
    __shared__ float fs[32][128];
    __shared__ float sig[128];
    const int row0 = blockIdx.x * 32;
    const int t = threadIdx.x;
    if (t < 128) sig[t] = 1.f / (1.f + expf(-mask[t]));
    __syncthreads();
    for (int idx = t; idx < 32 * 128; idx += 256) {
        int r = idx >> 7, c = idx & 127;
        int grow = row0 + r;
        fs[r][c] = (grow < N_NODES) ? feat[grow * 128 + c] * sig[c] : 0.f;
    }
    __syncthreads();
    const int j = t & 127;
    const int g = t >> 7;
    float acc[16];
#pragma unroll
    for (int r = 0; r < 16; r++) acc[r] = 0.f;
    for (int k = 0; k < 128; k += 4) {
        float w0 = W[(k + 0) * 128 + j];
        float w1 = W[(k + 1) * 128 + j];
        float w2 = W[(k + 2) * 128 + j];
        float w3 = W[(k + 3) * 128 + j];
#pragma unroll
        for (int r = 0; r < 16; r++) {
            const float4 f4 = *(const float4*)&fs[g * 16 + r][k];
            acc[r] = fmaf(f4.x, w0, acc[r]);
            acc[r] = fmaf(f4.y, w1, acc[r]);
            acc[r] = fmaf(f4.z, w2, acc[r]);
            acc[r] = fmaf(f4.w, w3, acc[r]);
        }
    }
    const float bj = b[j];
    const int plane = j >> 5, off = j & 31;
    __half* hp = h16 + (size_t)plane * (N_NODES * 32) + off;
#pragma unroll
    for (int r = 0; r < 16; r++) {
        int grow = row0 + g * 16 + r;
        if (grow < N_NODES) hp[grow * 32] = __float2half(acc[r] + bj);
    }
}

// per-node attention dots from quarter-major h16
__global__ __launch_bounds__(256) void k_sdots(const __half* __restrict__ h16,
                                               const float* __restrict__ attn_w,
                                               float* __restrict__ s_src,
                                               float* __restrict__ s_dst) {
    int wid = (blockIdx.x * 256 + threadIdx.x) >> 6;
    int lane = threadIdx.x & 63;
    if (wid >= N_NODES) return;
    int plane = lane >> 4, pp = lane & 15;
    __half2 hv2 = ((const __half2*)h16)[(size_t)plane * (N_NODES * 16) + wid * 16 + pp];
    float2 hv = __half22float2(hv2);
    float2 a0 = *(const float2*)&attn_w[lane * 2];
    float2 a1 = *(const float2*)&attn_w[128 + lane * 2];
    float ps = hv.x * a0.x + hv.y * a0.y;
    float pd = hv.x * a1.x + hv.y * a1.y;
#pragma unroll
    for (int off = 32; off > 0; off >>= 1) {
        ps += __shfl_down(ps, off);
        pd += __shfl_down(pd, off);
    }
    if (lane == 0) { s_src[wid] = ps; s_dst[wid] = pd; }
}

// binning: grid (NCH, SPLIT). Block (c, sp) reads chunk c's edges and keeps
// those whose bucket falls in its quartile -> LDS cursors stay block-private,
// cells stay single-writer, and 400x512 threads fill the whole device.
__global__ __launch_bounds__(512) void k_place(const int* __restrict__ src,
                                               const int* __restrict__ dst,
                                               int* __restrict__ cnt,
                                               unsigned* __restrict__ gep) {
    __shared__ int cur[BPS];
    const int c = blockIdx.x, sp = blockIdx.y, t = threadIdx.x;
    const int b0 = sp * BPS;
    for (int i = t; i < BPS; i += 512) cur[i] = 0;
    __syncthreads();
    const int q0 = c * (EPC / 4);
    for (int q = t; q < EPC / 4; q += 512) {
        int4 s4 = ((const int4*)src)[q0 + q];
        int4 d4 = ((const int4*)dst)[q0 + q];
        int ss[4] = {s4.x, s4.y, s4.z, s4.w};
        int dd[4] = {d4.x, d4.y, d4.z, d4.w};
#pragma unroll
        for (int k = 0; k < 4; k++) {
            int d = dd[k];
            int bkt = d / NPB;           // magic-mul
            if (bkt >= b0 && bkt < b0 + BPS) {
                int dl = d - bkt * NPB;
                int r = atomicAdd(&cur[bkt - b0], 1);
                if (r < CAPC)
                    gep[(bkt * NCH + c) * CAPC + r] = ((unsigned)ss[k] << 5) | (unsigned)dl;
            }
        }
    }
    __syncthreads();
    for (int i = t; i < BPS; i += 512) cnt[c * NB + b0 + i] = min(cur[i], CAPC);
}

// fused gather-sort-softmax-aggregate: one block per (bucket, dim-quarter).
// Quarter is derived from blockIdx&7 so each XCD's L2 sees one 3.2 MB slice.
__global__ __launch_bounds__(256) void k_agg(const __half* __restrict__ h16,
                                             const float* __restrict__ s_src,
                                             const float* __restrict__ s_dst,
                                             const float* __restrict__ attn_b,
                                             const int* __restrict__ cnt,
                                             const unsigned* __restrict__ gep,
                                             float* __restrict__ out) {
    __shared__ unsigned raw[CAP_LDS];
    __shared__ unsigned srt[CAP_LDS];   // (src<<16)|fp16(w), grouped by node
    __shared__ int ccnt[NCH];
    __shared__ int coff[NCH + 1];
    __shared__ int hist[NPB];
    __shared__ int rp[NPB + 1];
    __shared__ int curn[NPB];
    __shared__ float sdl[NPB];
    const int blk = blockIdx.x;
    const int xcd = blk & 7;
    const int qq = xcd & 3;                          // dim quarter 0..3
    const int bkt = ((blk >> 3) << 1) + (xcd >> 2);  // bucket 0..1999
    const int t = threadIdx.x;
    const int wv = t >> 6, lane = t & 63;
    if (t < NCH) ccnt[t] = cnt[t * NB + bkt];
    if (t < NPB) { hist[t] = 0; sdl[t] = s_dst[bkt * NPB + t]; }
    __syncthreads();
    if (t < 64) {   // exclusive scan of 100 cell counts, wave 0
        int i0 = 2 * t, i1 = 2 * t + 1;
        int a0 = (i0 < NCH) ? ccnt[i0] : 0;
        int a1 = (i1 < NCH) ? ccnt[i1] : 0;
        int s = a0 + a1, incl = s;
#pragma unroll
        for (int off = 1; off < 64; off <<= 1) {
            int v = __shfl_up(incl, off);
            if (t >= off) incl += v;
        }
        int excl = incl - s;
        if (i0 < NCH) coff[i0] = excl;
        if (i1 < NCH) coff[i1] = excl + a0;
        if (t == 63) coff[NCH] = incl;
    }
    __syncthreads();
    int total = coff[NCH];
    if (total > CAP_LDS) total = CAP_LDS;
    const unsigned* gb = gep + (size_t)bkt * NCH * CAPC;
    for (int cc = wv; cc < NCH; cc += 4) {
        int n = ccnt[cc];
        if (lane < n) {
            int pos = coff[cc] + lane;
            if (pos < CAP_LDS) {
                unsigned e = gb[cc * CAPC + lane];
                raw[pos] = e;
                atomicAdd(&hist[e & 31], 1);
            }
        }
    }
    __syncthreads();
    if (t == 0) {
        int run = 0;
        for (int j = 0; j < NPB; j++) { rp[j] = run; curn[j] = run; run += hist[j]; }
        rp[NPB] = run;
    }
    __syncthreads();
    const float ab = attn_b[0];
    for (int i = t; i < total; i += 256) {
        unsigned e = raw[i];
        int dl = e & 31;
        int s = (int)(e >> 5);
        float sc = s_src[s] + sdl[dl] + ab;
        sc = sc >= 0.f ? sc : 0.01f * sc;   // leaky_relu; |sc| small, exp safe
        float w = expf(sc);
        int pos = atomicAdd(&curn[dl], 1);
        srt[pos] = ((unsigned)s << 16) | (unsigned)__half_as_ushort(__float2half(w));
    }
    __syncthreads();
    // gather: 16-lane subgroups, 4 edges/wave in flight, 2x unroll (8 loads)
    const int eg = lane >> 4;   // edge subgroup 0..3
    const int dp = lane & 15;   // half2 index within quarter (16 x 4B = 64B)
    const __half2* hq = (const __half2*)h16 + (size_t)qq * (N_NODES * 16) + dp;
    for (int n = wv; n < NPB; n += 4) {
        int lo = rp[n], hi = rp[n + 1];
        float ax = 0.f, ay = 0.f, dn = 0.f;
        int i = lo + eg;
        for (; i + 4 < hi; i += 8) {
            unsigned ea = srt[i], eb = srt[i + 4];
            __half2 va = hq[(ea >> 16) * 16];
            __half2 vb = hq[(eb >> 16) * 16];
            float wa = __half2float(__ushort_as_half((unsigned short)(ea & 0xFFFFu)));
            float wb = __half2float(__ushort_as_half((unsigned short)(eb & 0xFFFFu)));
            float2 fa = __half22float2(va), fb = __half22float2(vb);
            ax = fmaf(wa, fa.x, ax); ay = fmaf(wa, fa.y, ay);
            ax = fmaf(wb, fb.x, ax); ay = fmaf(wb, fb.y, ay);
            dn += wa + wb;
        }
        for (; i < hi; i += 4) {
            unsigned e = srt[i];
            __half2 v = hq[(e >> 16) * 16];
            float w = __half2float(__ushort_as_half((unsigned short)(e & 0xFFFFu)));
            float2 f = __half22float2(v);
            ax = fmaf(w, f.x, ax); ay = fmaf(w, f.y, ay);
            dn += w;
        }
        // reduce across the 4 subgroups (lanes dp, dp+16, dp+32, dp+48)
        ax += __shfl_xor(ax, 16); ax += __shfl_xor(ax, 32);
        ay += __shfl_xor(ay, 16); ay += __shfl_xor(ay, 32);
        dn += __shfl_xor(dn, 16); dn += __shfl_xor(dn, 32);
        if (eg == 0) {
            float inv = dn > 0.f ? 1.f / dn : 0.f;
            float2 o = {ax * inv, ay * inv};
            ((float2*)out)[(size_t)(bkt * NPB + n) * 64 + qq * 16 + dp] = o;
        }
    }
}

extern "C" void kernel_launch(void* const* d_in, const int* in_sizes, int n_in,
                              void* d_out, int out_size, void* d_ws, size_t ws_size,
                              hipStream_t stream) {
    const float* feat   = (const float*)d_in[0];
    const int*   src    = (const int*)d_in[1];
    const int*   dst    = (const int*)d_in[2];
    const float* W      = (const float*)d_in[3];
    const float* b      = (const float*)d_in[4];
    const float* attn_w = (const float*)d_in[5];
    const float* attn_b = (const float*)d_in[6];
    const float* mask   = (const float*)d_in[7];
    float* out = (float*)d_out;

    char* ws = (char*)d_ws;
    __half*   h16   = (__half*)(ws + 0);
    float*    s_src = (float*)(ws + 12800000);
    float*    s_dst = (float*)(ws + 13000000);
    int*      cnt   = (int*)(ws + 13200000);
    unsigned* gep   = (unsigned*)(ws + 14000000);

    k_project<<<(N_NODES + 31) / 32, 256, 0, stream>>>(feat, W, b, mask, h16);
    k_sdots<<<(N_NODES * 64 + 255) / 256, 256, 0, stream>>>(h16, attn_w, s_src, s_dst);
    k_place<<<dim3(NCH, SPLIT), 512, 0, stream>>>(src, dst, cnt, gep);
    k_agg<<<NB * 4, 256, 0, stream>>>(h16, s_src, s_dst, attn_b, cnt, gep, out);
}

// Round 6
// 224.536 us; speedup vs baseline: 1.2187x; 1.2187x over previous
//
#include <hip/hip_runtime.h>
#include <hip/hip_fp16.h>
#include <math.h>

#define N_NODES 50000
#define N_EDGES 1600000
#define NB 2000      // dst buckets; NB*NPB == N_NODES
#define NPB 25       // dst nodes per bucket (dstLocal in 5 bits)
#define NCH 100      // edge chunks
#define EPC 16000    // edges per chunk
#define CAPC 32      // slots per (bucket,chunk) cell: Poisson(8) + ~8 sigma
#define CAP_LDS 1280 // max edges per bucket (mean 800, +17 sigma)
#define SPLIT 4      // k_place: blocks per chunk (bucket-range partition)
#define BPS (NB / SPLIT)

// ---- workspace layout (bytes) ----
// h16    : 0           12,800,000  __half[N][128] row-major
// s_src  : 12,800,000     200,000  float[N]
// s_dst  : 13,000,000     200,000  float[N]
// cnt    : 13,200,000     800,000  int[NCH*NB] (chunk-major, fully rewritten)
// gep    : 14,000,000  25,600,000  u32[NB*NCH*CAPC] ((src<<5)|dstLocal)
// total 39,600,000 B

// h = (feat * sigmoid(mask)) @ W + b, fp32 math, fp16 store. 32 rows/block.
__global__ __launch_bounds__(256) void k_project(const float* __restrict__ feat,
                                                 const float* __restrict__ W,
                                                 const float* __restrict__ b,
                                                 const float* __restrict__ mask,
                                                 __half* __restrict__ h16) {
    __shared__ float fs[32][128];
    __shared__ float sig[128];
    const int row0 = blockIdx.x * 32;
    const int t = threadIdx.x;
    if (t < 128) sig[t] = 1.f / (1.f + expf(-mask[t]));
    __syncthreads();
    for (int idx = t; idx < 32 * 128; idx += 256) {
        int r = idx >> 7, c = idx & 127;
        int grow = row0 + r;
        fs[r][c] = (grow < N_NODES) ? feat[grow * 128 + c] * sig[c] : 0.f;
    }
    __syncthreads();
    const int j = t & 127;
    const int g = t >> 7;
    float acc[16];
#pragma unroll
    for (int r = 0; r < 16; r++) acc[r] = 0.f;
    for (int k = 0; k < 128; k += 4) {
        float w0 = W[(k + 0) * 128 + j];
        float w1 = W[(k + 1) * 128 + j];
        float w2 = W[(k + 2) * 128 + j];
        float w3 = W[(k + 3) * 128 + j];
#pragma unroll
        for (int r = 0; r < 16; r++) {
            const float4 f4 = *(const float4*)&fs[g * 16 + r][k];
            acc[r] = fmaf(f4.x, w0, acc[r]);
            acc[r] = fmaf(f4.y, w1, acc[r]);
            acc[r] = fmaf(f4.z, w2, acc[r]);
            acc[r] = fmaf(f4.w, w3, acc[r]);
        }
    }
    const float bj = b[j];
#pragma unroll
    for (int r = 0; r < 16; r++) {
        int grow = row0 + g * 16 + r;
        if (grow < N_NODES) h16[grow * 128 + j] = __float2half(acc[r] + bj);
    }
}

// per-node attention dots: s_src = h.aw[:128], s_dst = h.aw[128:]
__global__ __launch_bounds__(256) void k_sdots(const __half* __restrict__ h16,
                                               const float* __restrict__ attn_w,
                                               float* __restrict__ s_src,
                                               float* __restrict__ s_dst) {
    int wid = (blockIdx.x * 256 + threadIdx.x) >> 6;
    int lane = threadIdx.x & 63;
    if (wid >= N_NODES) return;
    float2 hv = __half22float2(((const __half2*)(h16 + wid * 128))[lane]);
    float2 a0 = *(const float2*)&attn_w[lane * 2];
    float2 a1 = *(const float2*)&attn_w[128 + lane * 2];
    float ps = hv.x * a0.x + hv.y * a0.y;
    float pd = hv.x * a1.x + hv.y * a1.y;
#pragma unroll
    for (int off = 32; off > 0; off >>= 1) {
        ps += __shfl_down(ps, off);
        pd += __shfl_down(pd, off);
    }
    if (lane == 0) { s_src[wid] = ps; s_dst[wid] = pd; }
}

// binning: grid (NCH, SPLIT). Block (c, sp) reads chunk c's edges and keeps
// those whose bucket falls in its quartile -> LDS cursors stay block-private,
// cells stay single-writer, and 400x512 threads fill the whole device.
__global__ __launch_bounds__(512) void k_place(const int* __restrict__ src,
                                               const int* __restrict__ dst,
                                               int* __restrict__ cnt,
                                               unsigned* __restrict__ gep) {
    __shared__ int cur[BPS];
    const int c = blockIdx.x, sp = blockIdx.y, t = threadIdx.x;
    const int b0 = sp * BPS;
    for (int i = t; i < BPS; i += 512) cur[i] = 0;
    __syncthreads();
    const int q0 = c * (EPC / 4);
    for (int q = t; q < EPC / 4; q += 512) {
        int4 s4 = ((const int4*)src)[q0 + q];
        int4 d4 = ((const int4*)dst)[q0 + q];
        int ss[4] = {s4.x, s4.y, s4.z, s4.w};
        int dd[4] = {d4.x, d4.y, d4.z, d4.w};
#pragma unroll
        for (int k = 0; k < 4; k++) {
            int d = dd[k];
            int bkt = d / NPB;           // magic-mul
            if (bkt >= b0 && bkt < b0 + BPS) {
                int dl = d - bkt * NPB;
                int r = atomicAdd(&cur[bkt - b0], 1);
                if (r < CAPC)
                    gep[(bkt * NCH + c) * CAPC + r] = ((unsigned)ss[k] << 5) | (unsigned)dl;
            }
        }
    }
    __syncthreads();
    for (int i = t; i < BPS; i += 512) cnt[c * NB + b0 + i] = min(cur[i], CAPC);
}

__device__ __forceinline__ void accum4(float4& a, float& dn, uint2 u, float w) {
    __half2 p0 = *(const __half2*)&u.x;
    __half2 p1 = *(const __half2*)&u.y;
    float2 f0 = __half22float2(p0), f1 = __half22float2(p1);
    a.x = fmaf(w, f0.x, a.x); a.y = fmaf(w, f0.y, a.y);
    a.z = fmaf(w, f1.x, a.z); a.w = fmaf(w, f1.y, a.w);
    dn += w;
}

__device__ __forceinline__ float wdec(unsigned e) {
    return __half2float(__ushort_as_half((unsigned short)(e & 0xFFFFu)));
}

// fused gather-sort-softmax-aggregate: one block per bucket (25 dst nodes).
// Gather: 32 lanes/edge, uint2 (8 B) per lane -> 2 edges per vmem instr;
// 4x unroll = 8 edges in flight per wave.
__global__ __launch_bounds__(256) void k_agg(const __half* __restrict__ h16,
                                             const float* __restrict__ s_src,
                                             const float* __restrict__ s_dst,
                                             const float* __restrict__ attn_b,
                                             const int* __restrict__ cnt,
                                             const unsigned* __restrict__ gep,
                                             float* __restrict__ out) {
    __shared__ unsigned raw[CAP_LDS];
    __shared__ unsigned srt[CAP_LDS];   // (src<<16)|fp16(w), grouped by node
    __shared__ int ccnt[NCH];
    __shared__ int coff[NCH + 1];
    __shared__ int hist[NPB];
    __shared__ int rp[NPB + 1];
    __shared__ int curn[NPB];
    __shared__ float sdl[NPB];
    const int bkt = blockIdx.x;
    const int t = threadIdx.x;
    const int wv = t >> 6, lane = t & 63;
    if (t < NCH) ccnt[t] = cnt[t * NB + bkt];
    if (t < NPB) { hist[t] = 0; sdl[t] = s_dst[bkt * NPB + t]; }
    __syncthreads();
    if (t < 64) {   // exclusive scan of 100 cell counts, wave 0
        int i0 = 2 * t, i1 = 2 * t + 1;
        int a0 = (i0 < NCH) ? ccnt[i0] : 0;
        int a1 = (i1 < NCH) ? ccnt[i1] : 0;
        int s = a0 + a1, incl = s;
#pragma unroll
        for (int off = 1; off < 64; off <<= 1) {
            int v = __shfl_up(incl, off);
            if (t >= off) incl += v;
        }
        int excl = incl - s;
        if (i0 < NCH) coff[i0] = excl;
        if (i1 < NCH) coff[i1] = excl + a0;
        if (t == 63) coff[NCH] = incl;
    }
    __syncthreads();
    int total = coff[NCH];
    if (total > CAP_LDS) total = CAP_LDS;
    const unsigned* gb = gep + (size_t)bkt * NCH * CAPC;
    for (int cc = wv; cc < NCH; cc += 4) {
        int n = ccnt[cc];
        if (lane < n) {
            int pos = coff[cc] + lane;
            if (pos < CAP_LDS) {
                unsigned e = gb[cc * CAPC + lane];
                raw[pos] = e;
                atomicAdd(&hist[e & 31], 1);
            }
        }
    }
    __syncthreads();
    if (t == 0) {
        int run = 0;
        for (int j = 0; j < NPB; j++) { rp[j] = run; curn[j] = run; run += hist[j]; }
        rp[NPB] = run;
    }
    __syncthreads();
    const float ab = attn_b[0];
    for (int i = t; i < total; i += 256) {
        unsigned e = raw[i];
        int dl = e & 31;
        int s = (int)(e >> 5);
        float sc = s_src[s] + sdl[dl] + ab;
        sc = sc >= 0.f ? sc : 0.01f * sc;   // leaky_relu; |sc| small, exp safe
        float w = expf(sc);
        int pos = atomicAdd(&curn[dl], 1);
        srt[pos] = ((unsigned)s << 16) | (unsigned)__half_as_ushort(__float2half(w));
    }
    __syncthreads();
    const int sub = lane >> 5;   // which edge of the pair (0/1)
    const int sl = lane & 31;    // dim quad: dims 4*sl .. 4*sl+3 (8 B)
    const uint2* hb = (const uint2*)h16;   // row stride = 32 uint2
    for (int n = wv; n < NPB; n += 4) {
        int lo = rp[n], hi = rp[n + 1];
        float4 a4 = {0.f, 0.f, 0.f, 0.f};
        float dn = 0.f;
        int i = lo + sub;
        for (; i + 6 < hi; i += 8) {
            unsigned e0 = srt[i], e1 = srt[i + 2], e2 = srt[i + 4], e3 = srt[i + 6];
            uint2 u0 = hb[(e0 >> 16) * 32 + sl];
            uint2 u1 = hb[(e1 >> 16) * 32 + sl];
            uint2 u2 = hb[(e2 >> 16) * 32 + sl];
            uint2 u3 = hb[(e3 >> 16) * 32 + sl];
            accum4(a4, dn, u0, wdec(e0));
            accum4(a4, dn, u1, wdec(e1));
            accum4(a4, dn, u2, wdec(e2));
            accum4(a4, dn, u3, wdec(e3));
        }
        for (; i < hi; i += 2) {
            unsigned e = srt[i];
            uint2 u = hb[(e >> 16) * 32 + sl];
            accum4(a4, dn, u, wdec(e));
        }
        // combine the two edge-subgroups (lane <-> lane^32)
        a4.x += __shfl_xor(a4.x, 32);
        a4.y += __shfl_xor(a4.y, 32);
        a4.z += __shfl_xor(a4.z, 32);
        a4.w += __shfl_xor(a4.w, 32);
        dn   += __shfl_xor(dn, 32);
        if (sub == 0) {
            float inv = dn > 0.f ? 1.f / dn : 0.f;
            float4 o = {a4.x * inv, a4.y * inv, a4.z * inv, a4.w * inv};
            ((float4*)out)[(size_t)(bkt * NPB + n) * 32 + sl] = o;
        }
    }
}

extern "C" void kernel_launch(void* const* d_in, const int* in_sizes, int n_in,
                              void* d_out, int out_size, void* d_ws, size_t ws_size,
                              hipStream_t stream) {
    const float* feat   = (const float*)d_in[0];
    const int*   src    = (const int*)d_in[1];
    const int*   dst    = (const int*)d_in[2];
    const float* W      = (const float*)d_in[3];
    const float* b      = (const float*)d_in[4];
    const float* attn_w = (const float*)d_in[5];
    const float* attn_b = (const float*)d_in[6];
    const float* mask   = (const float*)d_in[7];
    float* out = (float*)d_out;

    char* ws = (char*)d_ws;
    __half*   h16   = (__half*)(ws + 0);
    float*    s_src = (float*)(ws + 12800000);
    float*    s_dst = (float*)(ws + 13000000);
    int*      cnt   = (int*)(ws + 13200000);
    unsigned* gep   = (unsigned*)(ws + 14000000);

    k_project<<<(N_NODES + 31) / 32, 256, 0, stream>>>(feat, W, b, mask, h16);
    k_sdots<<<(N_NODES * 64 + 255) / 256, 256, 0, stream>>>(h16, attn_w, s_src, s_dst);
    k_place<<<dim3(NCH, SPLIT), 512, 0, stream>>>(src, dst, cnt, gep);
    k_agg<<<NB, 256, 0, stream>>>(h16, s_src, s_dst, attn_b, cnt, gep, out);
}